// Round 1
// baseline (307.098 us; speedup 1.0000x reference)
//
#include <hip/hip_runtime.h>
#include <math.h>

#define B_N 2048
#define L_N 64
#define D_N 256   // EMBED_DIM
#define U_N 512   // UNITS
#define NB  4     // batches per attn block (cross-b pipeline depth)

typedef __attribute__((ext_vector_type(8))) short bf16x8;   // 8 bf16 = 4 VGPRs
typedef __attribute__((ext_vector_type(4))) float f32x4;    // MFMA 16x16 acc

// tanh(x) = 1 - 2/(2^(x*2*log2e)+1)
__device__ __forceinline__ float fast_tanh(float x) {
    float e = __builtin_amdgcn_exp2f(x * 2.8853900817779268f);
    float r = __builtin_amdgcn_rcpf(e + 1.0f);
    return fmaf(-2.0f, r, 1.0f);
}
// fp32 -> bf16 round-to-nearest-even
__device__ __forceinline__ ushort f2bf(float x) {
    uint b = __float_as_uint(x);
    uint r = (b + 0x7FFF + ((b >> 16) & 1)) >> 16;
    return (ushort)r;
}
__device__ __forceinline__ float bf2f(ushort u) {
    uint v = ((uint)u) << 16;
    return __uint_as_float(v);
}

// ---------------------------------------------------------------------------
// K0: pack W1 [256,512] and W2 [512,512] fp32 -> bf16 MFMA B-fragment order.
// chunk g = (ntg*KS + ks)*64 + lane holds W[ks*32 + (lane>>4)*8 + j][ntg*16 + (lane&15)]
// ---------------------------------------------------------------------------
__global__ __launch_bounds__(256) void pack_weights(
    const float* __restrict__ W1, const float* __restrict__ W2,
    ushort* __restrict__ W1p, ushort* __restrict__ W2p)
{
    ushort tmp[8];
    if (blockIdx.x < 64) {
        int g = blockIdx.x * 256 + threadIdx.x;      // 0..16383
        int ntg = g >> 9, ks = (g >> 6) & 7, lane = g & 63;
        int n  = ntg * 16 + (lane & 15);
        int kb = ks * 32 + (lane >> 4) * 8;
#pragma unroll
        for (int j = 0; j < 8; ++j) tmp[j] = f2bf(W1[(kb + j) * U_N + n]);
        *(uint4*)&W1p[(size_t)g * 8] = *(uint4*)tmp;
    } else {
        int g = (blockIdx.x - 64) * 256 + threadIdx.x;  // 0..32767
        int ntg = g >> 10, ks = (g >> 6) & 15, lane = g & 63;
        int n  = ntg * 16 + (lane & 15);
        int kb = ks * 32 + (lane >> 4) * 8;
#pragma unroll
        for (int j = 0; j < 8; ++j) tmp[j] = f2bf(W2[(kb + j) * U_N + n]);
        *(uint4*)&W2p[(size_t)g * 8] = *(uint4*)tmp;
    }
}

// ---------------------------------------------------------------------------
// K1: ph = hidden @ W2 + b1 + b2 via bf16 MFMA, stored bf16.
// grid (B/16, U/128) = (128,4) = 512 blocks. Wave: 32 u (2 n-tiles).
// ---------------------------------------------------------------------------
__global__ __launch_bounds__(256) void proj_h_mfma(
    const float* __restrict__ hidden, const ushort* __restrict__ W2p,
    const float* __restrict__ b1, const float* __restrict__ b2,
    ushort* __restrict__ ph)
{
    __shared__ ushort As[16 * 512];   // 16 KB

    const int t  = threadIdx.x;
    const int b0 = blockIdx.x * 16;
    const int u0 = blockIdx.y * 128;

#pragma unroll
    for (int i = 0; i < 4; ++i) {
        int f = t + i * 256;
        int m = f >> 6, c = f & 63;
        float4 x0 = *(const float4*)&hidden[(b0 + m) * U_N + c * 8];
        float4 x1 = *(const float4*)&hidden[(b0 + m) * U_N + c * 8 + 4];
        ushort tmp[8] = {f2bf(x0.x), f2bf(x0.y), f2bf(x0.z), f2bf(x0.w),
                         f2bf(x1.x), f2bf(x1.y), f2bf(x1.z), f2bf(x1.w)};
        *(uint4*)&As[(m * 64 + (c ^ (m & 7))) * 8] = *(uint4*)tmp;
    }
    __syncthreads();

    const int w = t >> 6, lane = t & 63;
    const int ml = lane & 15, q = lane >> 4;

    f32x4 acc[2];
#pragma unroll
    for (int nt = 0; nt < 2; ++nt) acc[nt] = (f32x4){0.f, 0.f, 0.f, 0.f};

    for (int ks = 0; ks < 16; ++ks) {
        int c = ks * 4 + q;
        bf16x8 a = *(const bf16x8*)&As[(ml * 64 + (c ^ (ml & 7))) * 8];
        bf16x8 bb[2];
#pragma unroll
        for (int nt = 0; nt < 2; ++nt) {
            int ntg = blockIdx.y * 8 + w * 2 + nt;
            bb[nt] = *(const bf16x8*)&W2p[(size_t)((ntg * 16 + ks) * 64 + lane) * 8];
        }
#pragma unroll
        for (int nt = 0; nt < 2; ++nt)
            acc[nt] = __builtin_amdgcn_mfma_f32_16x16x32_bf16(a, bb[nt], acc[nt], 0, 0, 0);
    }

#pragma unroll
    for (int nt = 0; nt < 2; ++nt) {
        int n = u0 + (w * 2 + nt) * 16 + ml;
        float bias = b1[n] + b2[n];
#pragma unroll
        for (int r = 0; r < 4; ++r)
            ph[(size_t)(b0 + q * 4 + r) * U_N + n] = f2bf(acc[nt][r] + bias);
    }
}

// ---------------------------------------------------------------------------
// K2: per-batch fused attention, bf16 MFMA — cross-b pipelined (T14 split).
// Each block handles NB=4 consecutive b. LDS feature tile double-buffered
// (2x32KB -> 2 blocks/CU, 8 waves/CU). Stage of b+1 is issue-early (16x
// global_load_dwordx4 into 64 VGPRs at top of b's compute) / write-late
// (f2bf + ds_write after the MFMA loop) so HBM latency hides under compute.
// W1p B-frag prefetch deepened to 2 (only 2 waves/SIMD now hide L2 latency).
// __launch_bounds__(256,2): cap 256 VGPR, est ~190 live (pf 64 + acc 32 +
// B-bufs 24 + a 16 + lp 16 + addr).
// ---------------------------------------------------------------------------
__global__ __launch_bounds__(256, 2) void attn_kernel(
    const float* __restrict__ features, const ushort* __restrict__ W1p,
    const float* __restrict__ V, const float* __restrict__ bV,
    const ushort* __restrict__ ph, float* __restrict__ out)
{
    __shared__ ushort As[2][64 * 256];   // 2 x 32 KB, chunk (m,c) at m*32 + (c ^ (m&31))
    __shared__ float lpart[4][64];
    __shared__ float wls[64];

    const int t    = threadIdx.x;
    const int w    = t >> 6;
    const int lane = t & 63;
    const int ml   = lane & 15;
    const int q    = lane >> 4;
    const int b0   = blockIdx.x * NB;

    float4 pf[16];   // prefetch regs: 256 B/thread = one 64x256 fp32 tile/block

#define ISSUE(bb) do {                                                        \
        const float* fb_ = features + (size_t)(bb) * (L_N * D_N);             \
        _Pragma("unroll")                                                     \
        for (int i = 0; i < 8; ++i) {                                         \
            int f_ = t + i * 256;                                             \
            int m_ = f_ >> 5, c_ = f_ & 31;                                   \
            pf[2*i]   = *(const float4*)&fb_[m_ * D_N + c_ * 8];              \
            pf[2*i+1] = *(const float4*)&fb_[m_ * D_N + c_ * 8 + 4];          \
        }                                                                     \
    } while (0)

#define WRITE(buf) do {                                                       \
        _Pragma("unroll")                                                     \
        for (int i = 0; i < 8; ++i) {                                         \
            int f_ = t + i * 256;                                             \
            int m_ = f_ >> 5, c_ = f_ & 31;                                   \
            float4 x0_ = pf[2*i], x1_ = pf[2*i+1];                            \
            ushort tmp_[8] = {f2bf(x0_.x), f2bf(x0_.y), f2bf(x0_.z), f2bf(x0_.w), \
                              f2bf(x1_.x), f2bf(x1_.y), f2bf(x1_.z), f2bf(x1_.w)}; \
            *(uint4*)&As[buf][(m_ * 32 + (c_ ^ (m_ & 31))) * 8] = *(uint4*)tmp_;  \
        }                                                                     \
    } while (0)

    // prologue: stage b0 into buffer 0
    ISSUE(b0);
    WRITE(0);
    __syncthreads();

    const ushort* W1w = W1p + (size_t)(w * 8) * 8 * 64 * 8;  // wave's 128-u strip
    int cur = 0;

    for (int bi = 0; bi < NB; ++bi) {
        const int b = b0 + bi;

        // issue next batch's feature loads NOW; they drain under the MFMA loop
        if (bi + 1 < NB) ISSUE(b + 1);
        __builtin_amdgcn_sched_barrier(0);   // pin the loads before the compute loop

        float lp[16];
#pragma unroll
        for (int j = 0; j < 16; ++j) lp[j] = 0.f;

        for (int uc = 0; uc < 4; ++uc) {
            f32x4 acc[4][2];
#pragma unroll
            for (int mt = 0; mt < 4; ++mt)
#pragma unroll
                for (int nt = 0; nt < 2; ++nt)
                    acc[mt][nt] = (f32x4){0.f, 0.f, 0.f, 0.f};

            // B-frag 2-deep double buffer: preload ks=0,1 pairs
            bf16x8 bf0[2], bf1[2], bfn[2];
#pragma unroll
            for (int nt = 0; nt < 2; ++nt) {
                bf0[nt] = *(const bf16x8*)&W1w[(size_t)(((uc * 2 + nt) * 8 + 0) * 64 + lane) * 8];
                bf1[nt] = *(const bf16x8*)&W1w[(size_t)(((uc * 2 + nt) * 8 + 1) * 64 + lane) * 8];
            }

            for (int ks = 0; ks < 8; ++ks) {
                if (ks < 6) {
#pragma unroll
                    for (int nt = 0; nt < 2; ++nt)
                        bfn[nt] = *(const bf16x8*)&W1w[(size_t)(((uc * 2 + nt) * 8 + ks + 2) * 64 + lane) * 8];
                }
                bf16x8 a[4];
#pragma unroll
                for (int mt = 0; mt < 4; ++mt) {
                    int m = mt * 16 + ml;
                    int c = ks * 4 + q;
                    a[mt] = *(const bf16x8*)&As[cur][(m * 32 + (c ^ (m & 31))) * 8];
                }
#pragma unroll
                for (int nt = 0; nt < 2; ++nt)
#pragma unroll
                    for (int mt = 0; mt < 4; ++mt)
                        acc[mt][nt] = __builtin_amdgcn_mfma_f32_16x16x32_bf16(
                            a[mt], bf0[nt], acc[mt][nt], 0, 0, 0);
                bf0[0] = bf1[0]; bf0[1] = bf1[1];
                bf1[0] = bfn[0]; bf1[1] = bfn[1];
            }

            // fold this 32-u chunk into persistent lp.  D: n=nt*16+ml, m=mt*16+q*4+r
#pragma unroll
            for (int nt = 0; nt < 2; ++nt) {
                int n = w * 128 + uc * 32 + nt * 16 + ml;
                float phv = bf2f(ph[(size_t)b * U_N + n]);
                float vv  = V[n];
#pragma unroll
                for (int mt = 0; mt < 4; ++mt)
#pragma unroll
                    for (int r = 0; r < 4; ++r) {
                        float s = fast_tanh(acc[mt][nt][r] + phv);
                        lp[mt * 4 + r] = fmaf(s, vv, lp[mt * 4 + r]);
                    }
            }
        }

        // one shuffle-reduce over the 16 n-lanes
#pragma unroll
        for (int off = 1; off <= 8; off <<= 1)
#pragma unroll
            for (int j = 0; j < 16; ++j)
                lp[j] += __shfl_xor(lp[j], off);

        // BARRIER A: all waves done reading As[cur^1] (last b's ctx) before overwrite
        __syncthreads();
        if (bi + 1 < NB) WRITE(cur ^ 1);   // write-late: loads landed long ago

        if (ml == 0) {
#pragma unroll
            for (int mt = 0; mt < 4; ++mt)
#pragma unroll
                for (int r = 0; r < 4; ++r)
                    lpart[w][mt * 16 + q * 4 + r] = lp[mt * 4 + r];
        }
        __syncthreads();   // BARRIER B

        if (t < 64) {
            float lsum = bV[0] + lpart[0][t] + lpart[1][t] + lpart[2][t] + lpart[3][t];
            float mx = lsum;
#pragma unroll
            for (int off = 32; off > 0; off >>= 1)
                mx = fmaxf(mx, __shfl_xor(mx, off));
            float e = __expf(lsum - mx);
            float ssum = e;
#pragma unroll
            for (int off = 32; off > 0; off >>= 1)
                ssum += __shfl_xor(ssum, off);
            float wt = e / ssum;
            wls[t] = wt;
            out[(size_t)B_N * D_N + (size_t)b * L_N + t] = wt;
        }
        __syncthreads();   // BARRIER C

        // context[d] = sum_l w_l * f[l][d], from LDS bf16 (t == d)
        float ctx = 0.f;
#pragma unroll 16
        for (int l = 0; l < L_N; ++l) {
            ushort u = As[cur][(l * 32 + ((t >> 3) ^ (l & 31))) * 8 + (t & 7)];
            ctx = fmaf(wls[l], bf2f(u), ctx);
        }
        out[(size_t)b * D_N + t] = ctx;

        cur ^= 1;
    }
#undef ISSUE
#undef WRITE
}

// ---------------------------------------------------------------------------
extern "C" void kernel_launch(void* const* d_in, const int* in_sizes, int n_in,
                              void* d_out, int out_size, void* d_ws, size_t ws_size,
                              hipStream_t stream) {
    const float* features = (const float*)d_in[0];
    const float* hidden   = (const float*)d_in[1];
    const float* W1       = (const float*)d_in[2];
    const float* b1       = (const float*)d_in[3];
    const float* W2       = (const float*)d_in[4];
    const float* b2       = (const float*)d_in[5];
    const float* V        = (const float*)d_in[6];
    const float* bV       = (const float*)d_in[7];
    float* out = (float*)d_out;

    // ws: ph bf16 2 MB @0 | W1p 256 KB @2M | W2p 512 KB @2.25M
    ushort* ph  = (ushort*)d_ws;
    ushort* W1p = (ushort*)((char*)d_ws + (size_t)B_N * U_N * 2);
    ushort* W2p = (ushort*)((char*)d_ws + (size_t)B_N * U_N * 2 + (size_t)D_N * U_N * 2);

    pack_weights<<<192, 256, 0, stream>>>(W1, W2, W1p, W2p);
    proj_h_mfma<<<dim3(B_N / 16, U_N / 128), 256, 0, stream>>>(hidden, W2p, b1, b2, ph);
    attn_kernel<<<B_N / NB, 256, 0, stream>>>(features, W1p, V, bV, ph, out);
}